// Round 4
// baseline (1029.720 us; speedup 1.0000x reference)
//
#include <hip/hip_runtime.h>

#define GN 4096
#define CAP 512
#define CAP2 320   // LDS edge cap; row nnz ~ 83 +/- 9
#define NGRAPH 64
#define NBLK 1024  // 4 blocks/CU x 256 CUs; co-resident by construction

struct ShmGemm { float As[16][66]; float Bs[16][68]; };
struct ShmAttn { float w0[4][CAP2]; float w1[4][CAP2]; int cols[4][CAP2]; float Ws[64][64]; };
struct ShmPool { int bnd[2]; float pooled[192]; float z[10]; float red[2]; };
union ShmU { ShmGemm g; ShmAttn a; ShmPool p; };

struct Params {
    const float* x; const float* adj; const int* batch;
    const float* W1; const float* b1; const float* a1w1; const float* a1b1;
    const float* a2w1; const float* a2b1;
    const float* W2; const float* b2; const float* a1w2; const float* a1b2;
    const float* a2w2; const float* a2b2;
    const float* W3; const float* b3; const float* a1w3; const float* a1b3;
    const float* a2w3; const float* a2b3;
    const float* Wf; const float* bf;
    float* out;
    int* csr_cnt; int* csr_col;
    float* s1A; float* s2iA; float* s1B; float* s2iB;
    float* fA; float* fB; float* hbuf; float* pbuf;
    int* bar;        // [0]=count, [1]=generation (memset to 0 each launch)
};

// ---------- manual grid barrier: generation-based, device scope -------------
// Requires all NBLK blocks co-resident (launch_bounds + LDS guarantee 4/CU).
__device__ __forceinline__ void grid_barrier(int* bar)
{
    __syncthreads();
    if (threadIdx.x == 0) {
        __threadfence();   // release: prior global writes visible device-wide
        int gen = __hip_atomic_load(&bar[1], __ATOMIC_RELAXED,
                                    __HIP_MEMORY_SCOPE_AGENT);
        int prev = __hip_atomic_fetch_add(&bar[0], 1, __ATOMIC_ACQ_REL,
                                          __HIP_MEMORY_SCOPE_AGENT);
        if (prev == NBLK - 1) {
            __hip_atomic_store(&bar[0], 0, __ATOMIC_RELAXED,
                               __HIP_MEMORY_SCOPE_AGENT);
            __hip_atomic_store(&bar[1], gen + 1, __ATOMIC_RELEASE,
                               __HIP_MEMORY_SCOPE_AGENT);
        } else {
            while (__hip_atomic_load(&bar[1], __ATOMIC_ACQUIRE,
                                     __HIP_MEMORY_SCOPE_AGENT) == gen)
                __builtin_amdgcn_s_sleep(2);
        }
        __threadfence();   // acquire: invalidate stale cached lines
    }
    __syncthreads();
}

// ---------- attention phase: wave-per-row (1 row/wave at NBLK=1024) ---------
// FUSE: epilogue computes next layer's f = x @ Wn + bn and its scores,
// writing the opposite (double-buffered) f/s1/s2i set.
template<bool FUSE>
__device__ __forceinline__ void attn_phase(
    ShmAttn& sa, int bid, int t,
    const float* __restrict__ f, const float* __restrict__ s1,
    const float* __restrict__ s2i, const int* __restrict__ cnt_,
    const int* __restrict__ col_, float* __restrict__ xout, int ocol0,
    const float* __restrict__ Wn, const float* __restrict__ bn,
    const float* __restrict__ a1w, const float* __restrict__ a1b,
    const float* __restrict__ a2w, const float* __restrict__ a2b,
    float* __restrict__ fO, float* __restrict__ s1O, float* __restrict__ s2iO)
{
    int wv = t >> 6, lane = t & 63;
    if constexpr (FUSE) {
        // Ws[k][c] = Wn[c>>5][k][c&31]
#pragma unroll
        for (int pp = 0; pp < 16; ++pp) {
            int idx = t + pp * 256;
            int k = idx >> 6, c = idx & 63;
            sa.Ws[k][c] = Wn[(size_t)(c >> 5) * 2048 + (size_t)k * 32 + (c & 31)];
        }
        __syncthreads();
    }
    int i = bid * 4 + wv;                  // one row per wave
    int cnt = cnt_[i]; if (cnt > CAP2) cnt = CAP2;
    const int* cols = col_ + (size_t)i * CAP;
    float s10 = s1[i], s11 = s1[GN + i];
    float m0 = -1e30f, m1 = -1e30f;
    for (int c = lane; c < cnt; c += 64) {
        int j = cols[c];
        sa.cols[wv][c] = j;
        float2 s2v = *(const float2*)&s2i[j * 2];
        float e0 = s10 + s2v.x; e0 = e0 > 0.f ? e0 : 0.01f * e0;
        float e1 = s11 + s2v.y; e1 = e1 > 0.f ? e1 : 0.01f * e1;
        sa.w0[wv][c] = e0; sa.w1[wv][c] = e1;
        m0 = fmaxf(m0, e0); m1 = fmaxf(m1, e1);
    }
#pragma unroll
    for (int off = 32; off; off >>= 1) {
        m0 = fmaxf(m0, __shfl_xor(m0, off));
        m1 = fmaxf(m1, __shfl_xor(m1, off));
    }
    float sum0 = 0.f, sum1 = 0.f;
    for (int c = lane; c < cnt; c += 64) {
        float v0 = __expf(sa.w0[wv][c] - m0); sa.w0[wv][c] = v0; sum0 += v0;
        float v1 = __expf(sa.w1[wv][c] - m1); sa.w1[wv][c] = v1; sum1 += v1;
    }
#pragma unroll
    for (int off = 32; off; off >>= 1) {
        sum0 += __shfl_xor(sum0, off);
        sum1 += __shfl_xor(sum1, off);
    }
    int head = lane >> 5;
    const float* wrow = head ? sa.w1[wv] : sa.w0[wv];
    float o = 0.f;
#pragma unroll 8
    for (int c = 0; c < cnt; ++c) {
        int j = sa.cols[wv][c];
        o += wrow[c] * f[(size_t)j * 64 + lane];
    }
    float denom = head ? sum1 : sum0;
    float v = o / denom;
    v = v > 0.f ? v : 0.f;
    xout[(size_t)i * 192 + ocol0 + lane] = v;
    if constexpr (FUSE) {
        float f2 = bn[lane];
#pragma unroll
        for (int k = 0; k < 64; ++k)
            f2 += __shfl(v, k) * sa.Ws[k][lane];
        fO[(size_t)i * 64 + lane] = f2;
        float p1 = f2 * a1w[lane], p2 = f2 * a2w[lane];
#pragma unroll
        for (int off = 16; off; off >>= 1) {
            p1 += __shfl_xor(p1, off);
            p2 += __shfl_xor(p2, off);
        }
        if ((lane & 31) == 0) {
            s1O[head * GN + i] = p1 + a1b[head];
            s2iO[i * 2 + head] = p2 + a2b[head];
        }
    }
}

// ---------- the whole GAT as one persistent kernel (manual grid sync) -------
__global__ __launch_bounds__(256, 4) void fused_gat(Params p)
{
    __shared__ ShmU shm;
    int t = threadIdx.x, bid = blockIdx.x;
    int wv = t >> 6, lane = t & 63;

    // ===== P0: layer-1 GEMM partials (blocks 0..511, NSPLIT=8, KS=64) =======
    // =====     + CSR build from adj   (blocks 512..1023, 2 rows/wave) =======
    if (bid < 512) {
        const int K = 512;
        int tile = bid >> 3, ks = bid & 7;
        int i0 = tile * 64;
        int tx = t & 15, ty = t >> 4;
        float acc[4][4] = {};
        for (int kc = ks * 64; kc < ks * 64 + 64; kc += 16) {
            {   // stage A: 64 rows x 16 k
                int m = t >> 2, k4 = (t & 3) * 4;
                float4 a4 = *(const float4*)&p.x[(size_t)(i0 + m) * K + kc + k4];
                shm.g.As[k4 + 0][m] = a4.x; shm.g.As[k4 + 1][m] = a4.y;
                shm.g.As[k4 + 2][m] = a4.z; shm.g.As[k4 + 3][m] = a4.w;
            }
            {   // stage B: 16 k x 64 cols; W layout [2][K][32]
                int kk = t >> 4, c0 = (t & 15) * 4;
                const float* wp = p.W1 + (size_t)(c0 >> 5) * K * 32
                                       + (size_t)(kc + kk) * 32 + (c0 & 31);
                *(float4*)&shm.g.Bs[kk][c0] = *(const float4*)wp;
            }
            __syncthreads();
#pragma unroll
            for (int kk = 0; kk < 16; ++kk) {
                float4 a4 = *(const float4*)&shm.g.As[kk][ty * 4];
                float4 b4 = *(const float4*)&shm.g.Bs[kk][tx * 4];
                float a[4] = {a4.x, a4.y, a4.z, a4.w};
                float b[4] = {b4.x, b4.y, b4.z, b4.w};
#pragma unroll
                for (int ii = 0; ii < 4; ++ii)
#pragma unroll
                    for (int jj = 0; jj < 4; ++jj) acc[ii][jj] += a[ii] * b[jj];
            }
            __syncthreads();
        }
#pragma unroll
        for (int ii = 0; ii < 4; ++ii) {
            int r = i0 + ty * 4 + ii;
            float4 v = {acc[ii][0], acc[ii][1], acc[ii][2], acc[ii][3]};
            *(float4*)&p.pbuf[((size_t)ks * GN + r) * 64 + tx * 4] = v;
        }
    } else {
        // CSR: one wave per 2 rows; lane owns 64 cols as 16 coalesced float4s
        int wid = (bid - 512) * 4 + wv;     // [0, 2048)
#pragma unroll
        for (int q = 0; q < 2; ++q) {
            int i = wid * 2 + q;
            const float* row = p.adj + (size_t)i * GN;
            unsigned long long mask = 0ull;
#pragma unroll
            for (int qq = 0; qq < 16; ++qq) {
                float4 v = *(const float4*)(row + qq * 256 + lane * 4);
                unsigned long long m = (v.x != 0.f ? 1ull : 0ull)
                                     | (v.y != 0.f ? 2ull : 0ull)
                                     | (v.z != 0.f ? 4ull : 0ull)
                                     | (v.w != 0.f ? 8ull : 0ull);
                mask |= m << (qq * 4);
            }
            int pc = __popcll(mask);
            int scan = pc;
#pragma unroll
            for (int off = 1; off < 64; off <<= 1) {
                int nn = __shfl_up(scan, off);
                if (lane >= off) scan += nn;
            }
            int pw = scan - pc;                 // exclusive prefix
            if (lane == 63) p.csr_cnt[i] = scan < CAP ? scan : CAP;
            int* gcols = p.csr_col + (size_t)i * CAP;
            while (mask) {
                int b = __ffsll(mask) - 1;
                mask &= mask - 1;
                int col = (b >> 2) * 256 + lane * 4 + (b & 3);
                if (pw < CAP) gcols[pw] = col;
                ++pw;
            }
        }
    }
    grid_barrier(p.bar);

    // ===== P1: reduce partials + bias -> fA, fused scores (blocks 0..255) ===
    if (bid < 256) {
        int r = bid * 16 + (t >> 4);
        int c0 = (t & 15) * 4;
        float vx = 0.f, vy = 0.f, vz = 0.f, vw = 0.f;
#pragma unroll
        for (int ks = 0; ks < 8; ++ks) {
            float4 q = *(const float4*)&p.pbuf[((size_t)ks * GN + r) * 64 + c0];
            vx += q.x; vy += q.y; vz += q.z; vw += q.w;
        }
        float4 bi = *(const float4*)&p.b1[c0];
        vx += bi.x; vy += bi.y; vz += bi.z; vw += bi.w;
        float4 v = {vx, vy, vz, vw};
        *(float4*)&p.fA[(size_t)r * 64 + c0] = v;
        float4 w1 = *(const float4*)&p.a1w1[c0];
        float4 w2 = *(const float4*)&p.a2w1[c0];
        float p1 = vx * w1.x + vy * w1.y + vz * w1.z + vw * w1.w;
        float p2 = vx * w2.x + vy * w2.y + vz * w2.z + vw * w2.w;
#pragma unroll
        for (int off = 1; off < 8; off <<= 1) {
            p1 += __shfl_xor(p1, off);
            p2 += __shfl_xor(p2, off);
        }
        if ((t & 7) == 0) {
            int head = (t >> 3) & 1;
            p.s1A[head * GN + r] = p1 + p.a1b1[head];
            p.s2iA[r * 2 + head] = p2 + p.a2b1[head];
        }
    }
    grid_barrier(p.bar);

    // ===== P2: attn layer 1 (reads A) + fused layer-2 linear (writes B) =====
    attn_phase<true>(shm.a, bid, t, p.fA, p.s1A, p.s2iA, p.csr_cnt, p.csr_col,
                     p.hbuf, 0, p.W2, p.b2, p.a1w2, p.a1b2, p.a2w2, p.a2b2,
                     p.fB, p.s1B, p.s2iB);
    grid_barrier(p.bar);

    // ===== P3: attn layer 2 (reads B) + fused layer-3 linear (writes A) =====
    attn_phase<true>(shm.a, bid, t, p.fB, p.s1B, p.s2iB, p.csr_cnt, p.csr_col,
                     p.hbuf, 64, p.W3, p.b3, p.a1w3, p.a1b3, p.a2w3, p.a2b3,
                     p.fA, p.s1A, p.s2iA);
    grid_barrier(p.bar);

    // ===== P4: attn layer 3 (reads A) ========================================
    attn_phase<false>(shm.a, bid, t, p.fA, p.s1A, p.s2iA, p.csr_cnt, p.csr_col,
                      p.hbuf, 128, nullptr, nullptr, nullptr, nullptr,
                      nullptr, nullptr, nullptr, nullptr, nullptr);
    grid_barrier(p.bar);

    // ===== P5: pool + classify (blocks 0..63) ================================
    if (bid < NGRAPH) {
        int g = bid;
        if (t == 0) {
            int lo = 0, hi = GN;
            while (lo < hi) { int mid = (lo + hi) >> 1; if (p.batch[mid] < g) lo = mid + 1; else hi = mid; }
            shm.p.bnd[0] = lo;
            hi = GN;
            while (lo < hi) { int mid = (lo + hi) >> 1; if (p.batch[mid] < g + 1) lo = mid + 1; else hi = mid; }
            shm.p.bnd[1] = lo;
        }
        __syncthreads();
        int s = shm.p.bnd[0], e = shm.p.bnd[1];
        if (t < 192) {
            float a0 = 0.f, a1 = 0.f, a2 = 0.f, a3 = 0.f;
            int n = s;
            for (; n + 3 < e; n += 4) {
                a0 += p.hbuf[(size_t)(n + 0) * 192 + t];
                a1 += p.hbuf[(size_t)(n + 1) * 192 + t];
                a2 += p.hbuf[(size_t)(n + 2) * 192 + t];
                a3 += p.hbuf[(size_t)(n + 3) * 192 + t];
            }
            for (; n < e; ++n) a0 += p.hbuf[(size_t)n * 192 + t];
            float acc = (a0 + a1) + (a2 + a3);
            shm.p.pooled[t] = (e > s) ? acc / (float)(e - s) : 0.f;
        }
        __syncthreads();
        if (t < 10) {
            float zt = p.bf[t];
            for (int c = 0; c < 192; ++c) zt += shm.p.pooled[c] * p.Wf[c * 10 + t];
            shm.p.z[t] = zt;
        }
        __syncthreads();
        if (t == 0) {
            float m = shm.p.z[0];
            for (int o = 1; o < 10; ++o) m = fmaxf(m, shm.p.z[o]);
            float ssum = 0.f;
            for (int o = 0; o < 10; ++o) ssum += __expf(shm.p.z[o] - m);
            shm.p.red[0] = m; shm.p.red[1] = ssum;
        }
        __syncthreads();
        if (t < 10) p.out[g * 10 + t] = __expf(shm.p.z[t] - shm.p.red[0]) / shm.p.red[1];
    }
}

extern "C" void kernel_launch(void* const* d_in, const int* in_sizes, int n_in,
                              void* d_out, int out_size, void* d_ws, size_t ws_size,
                              hipStream_t stream)
{
    char* base = (char*)d_ws;
    Params hp;
    hp.x    = (const float*)d_in[0];
    hp.adj  = (const float*)d_in[1];
    hp.batch= (const int*)d_in[2];
    hp.W1   = (const float*)d_in[3];
    hp.b1   = (const float*)d_in[4];
    hp.a1w1 = (const float*)d_in[5];
    hp.a1b1 = (const float*)d_in[6];
    hp.a2w1 = (const float*)d_in[7];
    hp.a2b1 = (const float*)d_in[8];
    hp.W2   = (const float*)d_in[9];
    hp.b2   = (const float*)d_in[10];
    hp.a1w2 = (const float*)d_in[11];
    hp.a1b2 = (const float*)d_in[12];
    hp.a2w2 = (const float*)d_in[13];
    hp.a2b2 = (const float*)d_in[14];
    hp.W3   = (const float*)d_in[15];
    hp.b3   = (const float*)d_in[16];
    hp.a1w3 = (const float*)d_in[17];
    hp.a1b3 = (const float*)d_in[18];
    hp.a2w3 = (const float*)d_in[19];
    hp.a2b3 = (const float*)d_in[20];
    hp.Wf   = (const float*)d_in[21];
    hp.bf   = (const float*)d_in[22];
    hp.out  = (float*)d_out;
    hp.csr_cnt = (int*)(base + 0);              // 16 KiB
    hp.s1A     = (float*)(base + 16384);        // 32 KiB
    hp.s2iA    = (float*)(base + 49152);        // 32 KiB
    hp.s1B     = (float*)(base + 81920);        // 32 KiB
    hp.s2iB    = (float*)(base + 114688);       // 32 KiB
    hp.fA      = (float*)(base + 147456);       // 1 MiB
    hp.fB      = (float*)(base + 1196032);      // 1 MiB
    hp.hbuf    = (float*)(base + 2244608);      // 3 MiB
    hp.pbuf    = (float*)(base + 5390336);      // 8 MiB (8 x 1 MiB partials)
    hp.csr_col = (int*)(base + 13778944);       // 8 MiB
    hp.bar     = (int*)(base + 22167552);       // 64 B barrier state
    (void)ws_size; (void)n_in; (void)in_sizes; (void)out_size;

    hipMemsetAsync(hp.bar, 0, 64, stream);
    fused_gat<<<NBLK, 256, 0, stream>>>(hp);
}

// Round 5
// 200.237 us; speedup vs baseline: 5.1425x; 5.1425x over previous
//
#include <hip/hip_runtime.h>

#define GN 4096
#define CAP 512
#define CAP2 320   // LDS edge cap; row nnz ~ 83 +/- 9
#define NGRAPH 64

// ---------- phase 0: layer-1 GEMM partials (blocks 0..511) ------------------
// ----------          + CSR build from adj   (blocks 512..1535) --------------
// GEMM: 64x64 tile, K-split 8. W layout [2][K][32]; col c -> head c>>5, feat c&31.
// CSR:  wave-per-row; lane owns 64 cols as 16 coalesced float4s -> 64-bit mask,
//       single 64-lane shfl scan, no atomics/barriers/LDS.
template<int K, int NSPLIT>
__global__ __launch_bounds__(256) void gemm_csr(
    const float* __restrict__ A, int lda, const float* __restrict__ W,
    float* __restrict__ pbuf,
    const float* __restrict__ adj, int* __restrict__ cnt_, int* __restrict__ col_)
{
    int t = threadIdx.x;
    if (blockIdx.x < 512) {
        __shared__ float As[16][66];
        __shared__ float Bs[16][68];
        const int KS = K / NSPLIT;
        int tile = blockIdx.x / NSPLIT, ks = blockIdx.x % NSPLIT;
        int i0 = tile * 64;
        int tx = t & 15, ty = t >> 4;
        float acc[4][4] = {};
        for (int kc = ks * KS; kc < ks * KS + KS; kc += 16) {
            {   // stage A: 64 rows x 16 k, float4 per thread
                int m = t >> 2, k4 = (t & 3) * 4;
                float4 a4 = *(const float4*)&A[(size_t)(i0 + m) * lda + kc + k4];
                As[k4 + 0][m] = a4.x; As[k4 + 1][m] = a4.y;
                As[k4 + 2][m] = a4.z; As[k4 + 3][m] = a4.w;
            }
            {   // stage B: 16 k x 64 cols, float4 per thread
                int kk = t >> 4, c0 = (t & 15) * 4;
                const float* wp = W + (size_t)(c0 >> 5) * K * 32
                                    + (size_t)(kc + kk) * 32 + (c0 & 31);
                *(float4*)&Bs[kk][c0] = *(const float4*)wp;
            }
            __syncthreads();
#pragma unroll
            for (int kk = 0; kk < 16; ++kk) {
                float4 a4 = *(const float4*)&As[kk][ty * 4];
                float4 b4 = *(const float4*)&Bs[kk][tx * 4];
                float a[4] = {a4.x, a4.y, a4.z, a4.w};
                float b[4] = {b4.x, b4.y, b4.z, b4.w};
#pragma unroll
                for (int ii = 0; ii < 4; ++ii)
#pragma unroll
                    for (int jj = 0; jj < 4; ++jj) acc[ii][jj] += a[ii] * b[jj];
            }
            __syncthreads();
        }
#pragma unroll
        for (int ii = 0; ii < 4; ++ii) {
            int r = i0 + ty * 4 + ii;
            float4 v = {acc[ii][0], acc[ii][1], acc[ii][2], acc[ii][3]};
            *(float4*)&pbuf[((size_t)ks * GN + r) * 64 + tx * 4] = v;
        }
    } else {
        // ---- CSR build: one wave per row ----
        int bid = blockIdx.x - 512;
        int wv = t >> 6, lane = t & 63;
        int i = bid * 4 + wv;
        const float* row = adj + (size_t)i * GN;
        unsigned long long mask = 0ull;
#pragma unroll
        for (int q = 0; q < 16; ++q) {
            float4 v = *(const float4*)(row + q * 256 + lane * 4);
            unsigned long long m = (v.x != 0.f ? 1ull : 0ull)
                                 | (v.y != 0.f ? 2ull : 0ull)
                                 | (v.z != 0.f ? 4ull : 0ull)
                                 | (v.w != 0.f ? 8ull : 0ull);
            mask |= m << (q * 4);
        }
        int pc = __popcll(mask);
        int scan = pc;
#pragma unroll
        for (int off = 1; off < 64; off <<= 1) {
            int nn = __shfl_up(scan, off);
            if (lane >= off) scan += nn;
        }
        int p = scan - pc;                      // exclusive prefix
        if (lane == 63) cnt_[i] = scan < CAP ? scan : CAP;
        int* gcols = col_ + (size_t)i * CAP;
        while (mask) {
            int b = __ffsll(mask) - 1;
            mask &= mask - 1;
            int col = (b >> 2) * 256 + lane * 4 + (b & 3);
            if (p < CAP) gcols[p] = col;
            ++p;
        }
    }
}

// ---------- reduce partials + bias -> f, fused scores -----------------------
// s1 layout [2][GN]; s2i interleaved [GN][2].
template<int NSPLIT>
__global__ __launch_bounds__(256) void reduce_scores(
    const float* __restrict__ pbuf, const float* __restrict__ bias,
    const float* __restrict__ a1w, const float* __restrict__ a1b,
    const float* __restrict__ a2w, const float* __restrict__ a2b,
    float* __restrict__ f, float* __restrict__ s1, float* __restrict__ s2i)
{
    int t = threadIdx.x;
    int r = blockIdx.x * 16 + (t >> 4);
    int c0 = (t & 15) * 4;
    float vx = 0.f, vy = 0.f, vz = 0.f, vw = 0.f;
#pragma unroll
    for (int ks = 0; ks < NSPLIT; ++ks) {
        float4 p = *(const float4*)&pbuf[((size_t)ks * GN + r) * 64 + c0];
        vx += p.x; vy += p.y; vz += p.z; vw += p.w;
    }
    float4 bi = *(const float4*)&bias[c0];
    vx += bi.x; vy += bi.y; vz += bi.z; vw += bi.w;
    float4 v = {vx, vy, vz, vw};
    *(float4*)&f[(size_t)r * 64 + c0] = v;
    float4 w1 = *(const float4*)&a1w[c0];
    float4 w2 = *(const float4*)&a2w[c0];
    float p1 = vx * w1.x + vy * w1.y + vz * w1.z + vw * w1.w;
    float p2 = vx * w2.x + vy * w2.y + vz * w2.z + vw * w2.w;
#pragma unroll
    for (int off = 1; off < 8; off <<= 1) {
        p1 += __shfl_xor(p1, off);
        p2 += __shfl_xor(p2, off);
    }
    if ((t & 7) == 0) {
        int head = (t >> 3) & 1;
        s1[head * GN + r] = p1 + a1b[head];
        s2i[r * 2 + head] = p2 + a2b[head];
    }
}

// ---------- attention: 2 waves per row, 2 rows/block, 8 blocks/CU -----------
// Halves every per-wave serial chain vs 1-wave-per-row; 8192 waves = 8/SIMD
// hides L2 gather latency. 3 cheap __syncthreads for cross-wave combine.
// FUSE: epilogue (row's wave 0) computes next layer's f = x @ Wn + bn and its
// scores, writing the opposite (double-buffered) f/s1/s2i set. Wn read
// directly from L2 (16 KB, hot) - no LDS staging, keeps LDS at 8.8 KB.
template<bool FUSE>
__global__ __launch_bounds__(256, 8) void attn_wpr2(
    const float* __restrict__ f, const float* __restrict__ s1,
    const float* __restrict__ s2i, const int* __restrict__ cnt_,
    const int* __restrict__ col_, float* __restrict__ xout, int ocol0,
    const float* __restrict__ Wn, const float* __restrict__ bn,
    const float* __restrict__ a1w, const float* __restrict__ a1b,
    const float* __restrict__ a2w, const float* __restrict__ a2b,
    float* __restrict__ fO, float* __restrict__ s1O, float* __restrict__ s2iO)
{
    __shared__ float w0[2][CAP2], w1[2][CAP2];
    __shared__ int colsS[2][CAP2];
    __shared__ float red[2][2][4];    // [row][half][m0,m1,s0,s1]
    __shared__ float part[2][2][64];  // [row][half][lane]
    int t = threadIdx.x, wv = t >> 6, lane = t & 63;
    int r = wv >> 1;                  // row slot within block
    int h = wv & 1;                   // half index
    int i = blockIdx.x * 2 + r;
    int cnt = cnt_[i]; if (cnt > CAP2) cnt = CAP2;
    const int* cols = col_ + (size_t)i * CAP;
    float s10 = s1[i], s11 = s1[GN + i];
    float m0 = -1e30f, m1 = -1e30f;
    // scores: wave h covers c = h*64+lane step 128 (~1 iteration each)
    for (int c = h * 64 + lane; c < cnt; c += 128) {
        int j = cols[c];
        colsS[r][c] = j;
        float2 s2v = *(const float2*)&s2i[j * 2];
        float e0 = s10 + s2v.x; e0 = e0 > 0.f ? e0 : 0.01f * e0;
        float e1 = s11 + s2v.y; e1 = e1 > 0.f ? e1 : 0.01f * e1;
        w0[r][c] = e0; w1[r][c] = e1;
        m0 = fmaxf(m0, e0); m1 = fmaxf(m1, e1);
    }
#pragma unroll
    for (int off = 32; off; off >>= 1) {
        m0 = fmaxf(m0, __shfl_xor(m0, off));
        m1 = fmaxf(m1, __shfl_xor(m1, off));
    }
    if (lane == 0) { red[r][h][0] = m0; red[r][h][1] = m1; }
    __syncthreads();
    m0 = fmaxf(red[r][0][0], red[r][1][0]);
    m1 = fmaxf(red[r][0][1], red[r][1][1]);
    float sum0 = 0.f, sum1 = 0.f;
    for (int c = h * 64 + lane; c < cnt; c += 128) {
        float v0 = __expf(w0[r][c] - m0); w0[r][c] = v0; sum0 += v0;
        float v1 = __expf(w1[r][c] - m1); w1[r][c] = v1; sum1 += v1;
    }
#pragma unroll
    for (int off = 32; off; off >>= 1) {
        sum0 += __shfl_xor(sum0, off);
        sum1 += __shfl_xor(sum1, off);
    }
    if (lane == 0) { red[r][h][2] = sum0; red[r][h][3] = sum1; }
    __syncthreads();
    sum0 = red[r][0][2] + red[r][1][2];
    sum1 = red[r][0][3] + red[r][1][3];
    int head = lane >> 5;
    const float* wrow = head ? w1[r] : w0[r];
    // PV: each half-wave strides 2 over edges (~42 serial iterations)
    float o = 0.f;
#pragma unroll 8
    for (int c = h; c < cnt; c += 2) {
        int j = colsS[r][c];
        o += wrow[c] * f[(size_t)j * 64 + lane];
    }
    part[r][h][lane] = o;
    __syncthreads();
    if (h == 0) {
        o = part[r][0][lane] + part[r][1][lane];
        float denom = head ? sum1 : sum0;
        float v = o / denom;
        v = v > 0.f ? v : 0.f;
        xout[(size_t)i * 192 + ocol0 + lane] = v;
        if constexpr (FUSE) {
            // fused next-layer linear + scores; Wn[(c>>5)*2048 + k*32 + (c&31)]
            const float* wp = Wn + (size_t)(lane >> 5) * 2048 + (lane & 31);
            float f2 = bn[lane];
#pragma unroll 8
            for (int k = 0; k < 64; ++k)
                f2 += __shfl(v, k) * wp[(size_t)k * 32];
            fO[(size_t)i * 64 + lane] = f2;
            float p1 = f2 * a1w[lane], p2 = f2 * a2w[lane];
#pragma unroll
            for (int off = 16; off; off >>= 1) {
                p1 += __shfl_xor(p1, off);
                p2 += __shfl_xor(p2, off);
            }
            if ((lane & 31) == 0) {
                s1O[head * GN + i] = p1 + a1b[head];
                s2iO[i * 2 + head] = p2 + a2b[head];
            }
        }
    }
}

// ---------- fused pooling + classifier --------------------------------------
__global__ __launch_bounds__(192) void pool_classify(
    const float* __restrict__ hbuf, const int* __restrict__ batch,
    const float* __restrict__ Wf, const float* __restrict__ bfb,
    float* __restrict__ out)
{
    __shared__ int bnd[2];
    __shared__ float pooled[192];
    __shared__ float z[10];
    __shared__ float red[2];
    int g = blockIdx.x, t = threadIdx.x;
    if (t == 0) {
        int lo = 0, hi = GN;
        while (lo < hi) { int mid = (lo + hi) >> 1; if (batch[mid] < g) lo = mid + 1; else hi = mid; }
        bnd[0] = lo;
        hi = GN;
        while (lo < hi) { int mid = (lo + hi) >> 1; if (batch[mid] < g + 1) lo = mid + 1; else hi = mid; }
        bnd[1] = lo;
    }
    __syncthreads();
    int s = bnd[0], e = bnd[1];
    float a0 = 0.f, a1 = 0.f, a2 = 0.f, a3 = 0.f;
    int n = s;
    for (; n + 3 < e; n += 4) {
        a0 += hbuf[(size_t)(n + 0) * 192 + t];
        a1 += hbuf[(size_t)(n + 1) * 192 + t];
        a2 += hbuf[(size_t)(n + 2) * 192 + t];
        a3 += hbuf[(size_t)(n + 3) * 192 + t];
    }
    for (; n < e; ++n) a0 += hbuf[(size_t)n * 192 + t];
    float acc = (a0 + a1) + (a2 + a3);
    pooled[t] = (e > s) ? acc / (float)(e - s) : 0.f;
    __syncthreads();
    if (t < 10) {
        float zt = bfb[t];
        for (int c = 0; c < 192; ++c) zt += pooled[c] * Wf[c * 10 + t];
        z[t] = zt;
    }
    __syncthreads();
    if (t == 0) {
        float m = z[0];
        for (int o = 1; o < 10; ++o) m = fmaxf(m, z[o]);
        float ssum = 0.f;
        for (int o = 0; o < 10; ++o) ssum += __expf(z[o] - m);
        red[0] = m; red[1] = ssum;
    }
    __syncthreads();
    if (t < 10) out[g * 10 + t] = __expf(z[t] - red[0]) / red[1];
}

extern "C" void kernel_launch(void* const* d_in, const int* in_sizes, int n_in,
                              void* d_out, int out_size, void* d_ws, size_t ws_size,
                              hipStream_t stream)
{
    const float* x    = (const float*)d_in[0];
    const float* adj  = (const float*)d_in[1];
    const int*   batch= (const int*)d_in[2];
    const float* W1   = (const float*)d_in[3];
    const float* b1   = (const float*)d_in[4];
    const float* a1w1 = (const float*)d_in[5];
    const float* a1b1 = (const float*)d_in[6];
    const float* a2w1 = (const float*)d_in[7];
    const float* a2b1 = (const float*)d_in[8];
    const float* W2   = (const float*)d_in[9];
    const float* b2   = (const float*)d_in[10];
    const float* a1w2 = (const float*)d_in[11];
    const float* a1b2 = (const float*)d_in[12];
    const float* a2w2 = (const float*)d_in[13];
    const float* a2b2 = (const float*)d_in[14];
    const float* W3   = (const float*)d_in[15];
    const float* b3   = (const float*)d_in[16];
    const float* a1w3 = (const float*)d_in[17];
    const float* a1b3 = (const float*)d_in[18];
    const float* a2w3 = (const float*)d_in[19];
    const float* a2b3 = (const float*)d_in[20];
    const float* Wf   = (const float*)d_in[21];
    const float* bf   = (const float*)d_in[22];
    float* out = (float*)d_out;

    char* base = (char*)d_ws;
    int*   csr_cnt = (int*)(base + 0);              // 16 KiB
    float* s1A     = (float*)(base + 16384);        // 32 KiB
    float* s2iA    = (float*)(base + 49152);        // 32 KiB
    float* s1B     = (float*)(base + 81920);        // 32 KiB
    float* s2iB    = (float*)(base + 114688);       // 32 KiB
    float* fbufA   = (float*)(base + 147456);       // 1 MiB
    float* fbufB   = (float*)(base + 1196032);      // 1 MiB
    float* hbuf    = (float*)(base + 2244608);      // 3 MiB
    float* pbuf    = (float*)(base + 5390336);      // 8 MiB (8 x 1 MiB partials)
    int*   csr_col = (int*)(base + 13778944);       // 8 MiB
    (void)ws_size; (void)n_in; (void)in_sizes; (void)out_size;

    // phase 0: layer-1 GEMM (512 blocks) overlapped with CSR build (1024 blocks)
    gemm_csr<512, 8><<<1536, 256, 0, stream>>>(x, 512, W1, pbuf,
                                               adj, csr_cnt, csr_col);
    // layer-1 reduce + scores -> A buffers
    reduce_scores<8><<<GN / 16, 256, 0, stream>>>(pbuf, b1, a1w1, a1b1, a2w1, a2b1,
                                                  fbufA, s1A, s2iA);
    // layer-1 attention (reads A) + fused layer-2 linear (writes B)
    attn_wpr2<true><<<GN / 2, 256, 0, stream>>>(fbufA, s1A, s2iA, csr_cnt, csr_col,
                                                hbuf, 0,
                                                W2, b2, a1w2, a1b2, a2w2, a2b2,
                                                fbufB, s1B, s2iB);
    // layer-2 attention (reads B) + fused layer-3 linear (writes A)
    attn_wpr2<true><<<GN / 2, 256, 0, stream>>>(fbufB, s1B, s2iB, csr_cnt, csr_col,
                                                hbuf, 64,
                                                W3, b3, a1w3, a1b3, a2w3, a2b3,
                                                fbufA, s1A, s2iA);
    // layer-3 attention (reads A)
    attn_wpr2<false><<<GN / 2, 256, 0, stream>>>(fbufA, s1A, s2iA, csr_cnt, csr_col,
                                                 hbuf, 128,
                                                 nullptr, nullptr, nullptr, nullptr,
                                                 nullptr, nullptr, nullptr, nullptr,
                                                 nullptr);
    pool_classify<<<NGRAPH, 192, 0, stream>>>(hbuf, batch, Wf, bf, out);
}